// Round 18
// baseline (103.333 us; speedup 1.0000x reference)
//
#include <hip/hip_runtime.h>
#include <math.h>

// out[n] = sum_k exp2( t[n,k] ),  t[n,k] = sum_{j<10} P[n,j]*G[k,j]
// P = (x0^2,x1^2,x2^2, x0x1,x0x2,x1x2, x0,x1,x2, 1)
// G = h*(A00,A11,A22), 2h*(A01,A02,A12), L2E*(b0,b1,b2), h*c + log2(amp), h=-0.5*log2(e)
//
// MFMA f16 split-2 trick (one mfma_f32_16x16x32_f16 per 16x16 tile):
//   A cols [0..31] = [Phi(10) | Phi(10) | Plo(10) | 0 0]
//   B rows [0..31] = [Ghi(10) | Glo(10) | Ghi(10) | 0 0]
//
// exp2 via mean-zero Schraudolph: y = fma(t,2^23,B); v_cvt_u32_f32 saturates
// y<0 -> 0 (incl. -60000 pad gaussians); acc += bitcast<float>(u).
//
// ROUND 18 KEY CHANGE: PT=2 — each wave owns TWO point-tiles, so one
// ds_read_b128 of a B-tile feeds 2 MFMAs. LDS is a per-CU resource shared
// by all 4 SIMDs (~12cy per b128 read); at PT=1 the kernel needed ~20us of
// pure LDS-pipe occupancy per CU — the hidden serializer no amount of
// TLP/ILP could hide (r15-r17 nulls). Halving read count rebalances
// LDS (~10us) against the VALU issue floor (~10us).

typedef _Float16 half8 __attribute__((ext_vector_type(8)));
typedef float    f32x4 __attribute__((ext_vector_type(4)));

#define WPB     4    // waves per block
#define PT      2    // point-tiles per wave
#define CHUNK   8    // k-tiles per LDS buffer
#define NBUF    2    // double buffer

#define EXP_SCALE 8388608.0f        // 2^23
#define EXP_BIAS  1064880938.0f     // (127 - 0.0563) * 2^23, mean-zero bias

__device__ __forceinline__ unsigned cvt_u32_sat(float y) {
    unsigned u;
    asm("v_cvt_u32_f32 %0, %1" : "=v"(u) : "v"(y));   // saturates: y<0 -> 0
    return u;
}

__global__ __launch_bounds__(256) void gmf_precompute(
        const float* __restrict__ means,
        const float* __restrict__ log_scales,
        const float* __restrict__ quats,
        const float* __restrict__ log_amps,
        _Float16* __restrict__ Bf, int K, int KT) {
    int k = blockIdx.x * blockDim.x + threadIdx.x;
    if (k >= KT * 16) return;

    float gc[10];
    if (k < K) {
        float qw = quats[4*k+0], qx = quats[4*k+1], qy = quats[4*k+2], qz = quats[4*k+3];
        float qn = rsqrtf(qw*qw + qx*qx + qy*qy + qz*qz);
        qw *= qn; qx *= qn; qy *= qn; qz *= qn;

        float r00 = 1.f - 2.f*(qy*qy + qz*qz);
        float r01 = 2.f*(qx*qy - qw*qz);
        float r02 = 2.f*(qx*qz + qw*qy);
        float r10 = 2.f*(qx*qy + qw*qz);
        float r11 = 1.f - 2.f*(qx*qx + qz*qz);
        float r12 = 2.f*(qy*qz - qw*qx);
        float r20 = 2.f*(qx*qz - qw*qy);
        float r21 = 2.f*(qy*qz + qw*qx);
        float r22 = 1.f - 2.f*(qx*qx + qy*qy);

        float s0 = fminf(fmaxf(expf(log_scales[3*k+0]), 1e-5f), 100.f);
        float s1 = fminf(fmaxf(expf(log_scales[3*k+1]), 1e-5f), 100.f);
        float s2 = fminf(fmaxf(expf(log_scales[3*k+2]), 1e-5f), 100.f);
        float v0 = s0*s0, v1 = s1*s1, v2 = s2*s2;

        float S00 = r00*r00*v0 + r01*r01*v1 + r02*r02*v2 + 1e-5f;
        float S11 = r10*r10*v0 + r11*r11*v1 + r12*r12*v2 + 1e-5f;
        float S22 = r20*r20*v0 + r21*r21*v1 + r22*r22*v2 + 1e-5f;
        float S01 = r00*r10*v0 + r01*r11*v1 + r02*r12*v2;
        float S02 = r00*r20*v0 + r01*r21*v1 + r02*r22*v2;
        float S12 = r10*r20*v0 + r11*r21*v1 + r12*r22*v2;

        float c00 = S11*S22 - S12*S12;
        float c01 = S02*S12 - S01*S22;
        float c02 = S01*S12 - S02*S11;
        float det = S00*c00 + S01*c01 + S02*c02;
        float id  = 1.f/det;
        float A00 = c00*id, A01 = c01*id, A02 = c02*id;
        float A11 = (S00*S22 - S02*S02)*id;
        float A12 = (S01*S02 - S00*S12)*id;
        float A22 = (S00*S11 - S01*S01)*id;

        float m0 = means[3*k+0], m1 = means[3*k+1], m2 = means[3*k+2];
        float b0 = A00*m0 + A01*m1 + A02*m2;
        float b1 = A01*m0 + A11*m1 + A12*m2;
        float b2 = A02*m0 + A12*m1 + A22*m2;
        float cc = b0*m0 + b1*m1 + b2*m2;

        float la = fminf(fmaxf(log_amps[k], -10.f), 6.f);
        const float L2E = 1.4426950408889634f;
        const float h = -0.5f * L2E;

        gc[0] = h*A00; gc[1] = h*A11; gc[2] = h*A22;
        gc[3] = 2.f*h*A01; gc[4] = 2.f*h*A02; gc[5] = 2.f*h*A12;
        gc[6] = L2E*b0; gc[7] = L2E*b1; gc[8] = L2E*b2;
        gc[9] = h*cc + L2E*la;
    } else {
        #pragma unroll
        for (int j = 0; j < 10; ++j) gc[j] = 0.f;
        gc[9] = -60000.f;   // pad gaussian -> saturates to 0 in fast exp2
    }

    _Float16 gh[10], gl[10];
    #pragma unroll
    for (int j = 0; j < 10; ++j) {
        gh[j] = (_Float16)gc[j];
        gl[j] = (_Float16)(gc[j] - (float)gh[j]);
    }

    int kt = k >> 4, c = k & 15;
    _Float16* dst = Bf + (size_t)kt * 64 * 8;
    #pragma unroll 32
    for (int r = 0; r < 32; ++r) {
        int lg = r >> 3, j = r & 7;
        _Float16 v = (r < 10) ? gh[r]
                   : (r < 20) ? gl[r-10]
                   : (r < 30) ? gh[r-20]
                   : (_Float16)0.f;
        dst[((size_t)lg*16 + c)*8 + j] = v;
    }
}

// ---- single-tile A-fragment builder ----
__device__ __forceinline__ half8 gmf_build_afr1(
        const float* __restrict__ x, int pt, int lane, int N, int PTtot) {
    int lr = lane & 15;
    int lg = lane >> 4;
    int n = pt * 16 + lr;
    float x0 = 0.f, x1 = 0.f, x2 = 0.f;
    if (pt < PTtot && n < N) { x0 = x[3*n]; x1 = x[3*n+1]; x2 = x[3*n+2]; }

    float P0 = x0*x0, P1 = x1*x1, P2 = x2*x2;
    float P3 = x0*x1, P4 = x0*x2, P5 = x1*x2;

    _Float16 h0 = (_Float16)P0, h1 = (_Float16)P1, h2 = (_Float16)P2;
    _Float16 h3 = (_Float16)P3, h4 = (_Float16)P4, h5 = (_Float16)P5;
    _Float16 h6 = (_Float16)x0, h7 = (_Float16)x1, h8 = (_Float16)x2;
    _Float16 h9 = (_Float16)1.f;
    _Float16 l0 = (_Float16)(P0 - (float)h0), l1 = (_Float16)(P1 - (float)h1);
    _Float16 l2 = (_Float16)(P2 - (float)h2), l3 = (_Float16)(P3 - (float)h3);
    _Float16 l4 = (_Float16)(P4 - (float)h4), l5 = (_Float16)(P5 - (float)h5);
    _Float16 l6 = (_Float16)(x0 - (float)h6), l7 = (_Float16)(x1 - (float)h7);
    _Float16 l8 = (_Float16)(x2 - (float)h8), l9 = (_Float16)0.f;
    _Float16 z  = (_Float16)0.f;

    half8 a;
    if      (lg == 0) a = (half8){h0,h1,h2,h3,h4,h5,h6,h7};
    else if (lg == 1) a = (half8){h8,h9,h0,h1,h2,h3,h4,h5};
    else if (lg == 2) a = (half8){h6,h7,h8,h9,l0,l1,l2,l3};
    else              a = (half8){l4,l5,l6,l7,l8,l9,z,z};
    return a;
}

#define GMF_EXPACC(CC, ACC)                                                     \
    {                                                                           \
        f32x4 y = __builtin_elementwise_fma((CC), vscale, vbias);               \
        (ACC).x += __uint_as_float(cvt_u32_sat(y.x));                           \
        (ACC).y += __uint_as_float(cvt_u32_sat(y.y));                           \
        (ACC).z += __uint_as_float(cvt_u32_sat(y.z));                           \
        (ACC).w += __uint_as_float(cvt_u32_sat(y.w));                           \
    }

__device__ __forceinline__ void gmf_epilogue1(
        f32x4 a, int pt, int lane, int N, int PTtot, float* __restrict__ out) {
    int lr = lane & 15;
    int lg = lane >> 4;
    #pragma unroll
    for (int m = 1; m <= 8; m <<= 1) {   // reduce over 16 cols
        a.x += __shfl_xor(a.x, m);
        a.y += __shfl_xor(a.y, m);
        a.z += __shfl_xor(a.z, m);
        a.w += __shfl_xor(a.w, m);
    }
    if (lr == 0 && pt < PTtot) {
        int n0 = pt * 16 + lg * 4;
        if (n0     < N) out[n0]     = a.x;
        if (n0 + 1 < N) out[n0 + 1] = a.y;
        if (n0 + 2 < N) out[n0 + 2] = a.z;
        if (n0 + 3 < N) out[n0 + 3] = a.w;
    }
}

// No-split main: one wave = PT point-tiles x ALL K. One B ds_read feeds PT
// MFMAs. Double-buffered LDS staging via global_load_lds.
__global__ __launch_bounds__(256, 8) void gmf_main_ns(
        const float* __restrict__ x,
        const _Float16* __restrict__ Bfh,
        float* __restrict__ out,
        int N, int KT, int PTtot) {
    __shared__ _Float16 lbs_raw[NBUF * CHUNK * 512];   // 16 KiB

    int tid  = threadIdx.x;
    int lane = tid & 63;
    int wid  = tid >> 6;
    int pt0  = (blockIdx.x * WPB + wid) * PT;
    int pt1  = pt0 + 1;
    bool active = pt0 < PTtot;

    half8 afr0 = gmf_build_afr1(x, pt0, lane, N, PTtot);
    half8 afr1 = gmf_build_afr1(x, pt1, lane, N, PTtot);
    f32x4 acc0 = {0.f, 0.f, 0.f, 0.f};
    f32x4 acc1 = {0.f, 0.f, 0.f, 0.f};
    const f32x4 czero  = {0.f, 0.f, 0.f, 0.f};
    const f32x4 vscale = {EXP_SCALE, EXP_SCALE, EXP_SCALE, EXP_SCALE};
    const f32x4 vbias  = {EXP_BIAS,  EXP_BIAS,  EXP_BIAS,  EXP_BIAS};

    int nchunks = (KT + CHUNK - 1) / CHUNK;

#define GMF_STAGE(BUF, KBASE, NK)                                               \
    {                                                                           \
        _Pragma("unroll")                                                       \
        for (int j = 0; j < 2; ++j) {                                           \
            int tile = wid * 2 + j;                                             \
            if (tile < (NK)) {   /* wave-uniform */                             \
                const _Float16* src = Bfh + ((size_t)((KBASE) + tile)) * 512    \
                                          + lane * 8;                           \
                __builtin_amdgcn_global_load_lds(                               \
                    (const __attribute__((address_space(1))) void*)src,         \
                    (__attribute__((address_space(3))) void*)                   \
                        (lbs_raw + ((BUF) * CHUNK + tile) * 512 + lane * 8),    \
                    16, 0, 0);                                                  \
            }                                                                   \
        }                                                                       \
    }

    // Prologue: stage chunk 0 into buf 0, wait.
    {
        int nk0 = min(CHUNK, KT);
        GMF_STAGE(0, 0, nk0)
    }
    __syncthreads();   // implicit vmcnt(0) drain before s_barrier

    for (int c = 0; c < nchunks; ++c) {
        int cb = c & 1;
        int kbase = c * CHUNK;
        int nk = min(CHUNK, KT - kbase);   // uniform across block

        // Issue next chunk's loads BEFORE compute: latency hides under MFMAs.
        if (c + 1 < nchunks) {
            int nk1 = min(CHUNK, KT - (c + 1) * CHUNK);
            GMF_STAGE(cb ^ 1, (c + 1) * CHUNK, nk1)
        }

        if (active) {
            const half8* cur = (const half8*)(lbs_raw + cb * CHUNK * 512);
            if (nk == CHUNK) {
                // 2-stage rotation, full unroll (renaming removes copies).
                half8 b = cur[lane];
                f32x4 cB0 = __builtin_amdgcn_mfma_f32_16x16x32_f16(afr0, b, czero, 0, 0, 0);
                f32x4 cB1 = __builtin_amdgcn_mfma_f32_16x16x32_f16(afr1, b, czero, 0, 0, 0);
                b = cur[64 + lane];
                f32x4 cA0 = __builtin_amdgcn_mfma_f32_16x16x32_f16(afr0, b, czero, 0, 0, 0);
                f32x4 cA1 = __builtin_amdgcn_mfma_f32_16x16x32_f16(afr1, b, czero, 0, 0, 0);
                #pragma unroll
                for (int i = 2; i < CHUNK; ++i) {
                    GMF_EXPACC(cB0, acc0)
                    GMF_EXPACC(cB1, acc1)
                    cB0 = cA0; cB1 = cA1;
                    b = cur[i * 64 + lane];
                    cA0 = __builtin_amdgcn_mfma_f32_16x16x32_f16(afr0, b, czero, 0, 0, 0);
                    cA1 = __builtin_amdgcn_mfma_f32_16x16x32_f16(afr1, b, czero, 0, 0, 0);
                }
                GMF_EXPACC(cB0, acc0)
                GMF_EXPACC(cB1, acc1)
                GMF_EXPACC(cA0, acc0)
                GMF_EXPACC(cA1, acc1)
            } else {
                for (int i = 0; i < nk; ++i) {
                    half8 b = cur[i * 64 + lane];
                    f32x4 c0 = __builtin_amdgcn_mfma_f32_16x16x32_f16(afr0, b, czero, 0, 0, 0);
                    f32x4 c1 = __builtin_amdgcn_mfma_f32_16x16x32_f16(afr1, b, czero, 0, 0, 0);
                    GMF_EXPACC(c0, acc0)
                    GMF_EXPACC(c1, acc1)
                }
            }
        }

        // One barrier per chunk: drains next-chunk loads AND protects buf reuse.
        __syncthreads();
    }

    if (active) {
        gmf_epilogue1(acc0, pt0, lane, N, PTtot, out);
        gmf_epilogue1(acc1, pt1, lane, N, PTtot, out);
    }
#undef GMF_STAGE
}

extern "C" void kernel_launch(void* const* d_in, const int* in_sizes, int n_in,
                              void* d_out, int out_size, void* d_ws, size_t ws_size,
                              hipStream_t stream) {
    const float* x          = (const float*)d_in[0];
    const float* means      = (const float*)d_in[1];
    const float* log_scales = (const float*)d_in[2];
    const float* quats      = (const float*)d_in[3];
    const float* log_amps   = (const float*)d_in[4];
    float* out = (float*)d_out;

    int K = in_sizes[4];
    int N = out_size;
    int KT = (K + 15) / 16;
    int PTtot = (N + 15) / 16;

    _Float16* Bf = (_Float16*)d_ws;   // KT tiles x 1KB

    gmf_precompute<<<(KT*16 + 255) / 256, 256, 0, stream>>>(
        means, log_scales, quats, log_amps, Bf, K, KT);

    int tiles_per_block = WPB * PT;
    int blocks = (PTtot + tiles_per_block - 1) / tiles_per_block;
    gmf_main_ns<<<blocks, 256, 0, stream>>>(x, Bf, out, N, KT, PTtot);
}

// Round 19
// 40.833 us; speedup vs baseline: 2.5306x; 2.5306x over previous
//
#include <hip/hip_runtime.h>
#include <math.h>

// out[n] = sum_k exp2( t[n,k] ),  t[n,k] = sum_{j<10} P[n,j]*G[k,j]
// P = (x0^2,x1^2,x2^2, x0x1,x0x2,x1x2, x0,x1,x2, 1)
// G = h*(A00,A11,A22), 2h*(A01,A02,A12), L2E*(b0,b1,b2), h*c + log2(amp), h=-0.5*log2(e)
//
// MFMA f16 split-2 trick (one mfma_f32_16x16x32_f16 per 16x16 tile):
//   A cols [0..31] = [Phi(10) | Phi(10) | Plo(10) | 0 0]
//   B rows [0..31] = [Ghi(10) | Glo(10) | Ghi(10) | 0 0]
//
// exp2 via mean-zero Schraudolph: y = fma(t,2^23,B); v_cvt_u32_f32 saturates
// y<0 -> 0 (incl. -60000 pad gaussians); acc += bitcast<float>(u).
//
// ROUND 19 = ROUND 18 FIXED: PT=2 (one ds_read_b128 feeds 2 MFMAs; halves
// per-CU LDS-pipe occupancy, the suspected ~20us serializer of r15-r17) but
// with __launch_bounds__(256,4): 128-VGPR budget. r18's (256,8) capped at
// 64 VGPRs and spilled ~264MB to scratch (WRITE_SIZE blowup, 103us).

typedef _Float16 half8 __attribute__((ext_vector_type(8)));
typedef float    f32x4 __attribute__((ext_vector_type(4)));

#define WPB     4    // waves per block
#define PT      2    // point-tiles per wave
#define CHUNK   8    // k-tiles per LDS buffer
#define NBUF    2    // double buffer

#define EXP_SCALE 8388608.0f        // 2^23
#define EXP_BIAS  1064880938.0f     // (127 - 0.0563) * 2^23, mean-zero bias

__device__ __forceinline__ unsigned cvt_u32_sat(float y) {
    unsigned u;
    asm("v_cvt_u32_f32 %0, %1" : "=v"(u) : "v"(y));   // saturates: y<0 -> 0
    return u;
}

__global__ __launch_bounds__(256) void gmf_precompute(
        const float* __restrict__ means,
        const float* __restrict__ log_scales,
        const float* __restrict__ quats,
        const float* __restrict__ log_amps,
        _Float16* __restrict__ Bf, int K, int KT) {
    int k = blockIdx.x * blockDim.x + threadIdx.x;
    if (k >= KT * 16) return;

    float gc[10];
    if (k < K) {
        float qw = quats[4*k+0], qx = quats[4*k+1], qy = quats[4*k+2], qz = quats[4*k+3];
        float qn = rsqrtf(qw*qw + qx*qx + qy*qy + qz*qz);
        qw *= qn; qx *= qn; qy *= qn; qz *= qn;

        float r00 = 1.f - 2.f*(qy*qy + qz*qz);
        float r01 = 2.f*(qx*qy - qw*qz);
        float r02 = 2.f*(qx*qz + qw*qy);
        float r10 = 2.f*(qx*qy + qw*qz);
        float r11 = 1.f - 2.f*(qx*qx + qz*qz);
        float r12 = 2.f*(qy*qz - qw*qx);
        float r20 = 2.f*(qx*qz - qw*qy);
        float r21 = 2.f*(qy*qz + qw*qx);
        float r22 = 1.f - 2.f*(qx*qx + qy*qy);

        float s0 = fminf(fmaxf(expf(log_scales[3*k+0]), 1e-5f), 100.f);
        float s1 = fminf(fmaxf(expf(log_scales[3*k+1]), 1e-5f), 100.f);
        float s2 = fminf(fmaxf(expf(log_scales[3*k+2]), 1e-5f), 100.f);
        float v0 = s0*s0, v1 = s1*s1, v2 = s2*s2;

        float S00 = r00*r00*v0 + r01*r01*v1 + r02*r02*v2 + 1e-5f;
        float S11 = r10*r10*v0 + r11*r11*v1 + r12*r12*v2 + 1e-5f;
        float S22 = r20*r20*v0 + r21*r21*v1 + r22*r22*v2 + 1e-5f;
        float S01 = r00*r10*v0 + r01*r11*v1 + r02*r12*v2;
        float S02 = r00*r20*v0 + r01*r21*v1 + r02*r22*v2;
        float S12 = r10*r20*v0 + r11*r21*v1 + r12*r22*v2;

        float c00 = S11*S22 - S12*S12;
        float c01 = S02*S12 - S01*S22;
        float c02 = S01*S12 - S02*S11;
        float det = S00*c00 + S01*c01 + S02*c02;
        float id  = 1.f/det;
        float A00 = c00*id, A01 = c01*id, A02 = c02*id;
        float A11 = (S00*S22 - S02*S02)*id;
        float A12 = (S01*S02 - S00*S12)*id;
        float A22 = (S00*S11 - S01*S01)*id;

        float m0 = means[3*k+0], m1 = means[3*k+1], m2 = means[3*k+2];
        float b0 = A00*m0 + A01*m1 + A02*m2;
        float b1 = A01*m0 + A11*m1 + A12*m2;
        float b2 = A02*m0 + A12*m1 + A22*m2;
        float cc = b0*m0 + b1*m1 + b2*m2;

        float la = fminf(fmaxf(log_amps[k], -10.f), 6.f);
        const float L2E = 1.4426950408889634f;
        const float h = -0.5f * L2E;

        gc[0] = h*A00; gc[1] = h*A11; gc[2] = h*A22;
        gc[3] = 2.f*h*A01; gc[4] = 2.f*h*A02; gc[5] = 2.f*h*A12;
        gc[6] = L2E*b0; gc[7] = L2E*b1; gc[8] = L2E*b2;
        gc[9] = h*cc + L2E*la;
    } else {
        #pragma unroll
        for (int j = 0; j < 10; ++j) gc[j] = 0.f;
        gc[9] = -60000.f;   // pad gaussian -> saturates to 0 in fast exp2
    }

    _Float16 gh[10], gl[10];
    #pragma unroll
    for (int j = 0; j < 10; ++j) {
        gh[j] = (_Float16)gc[j];
        gl[j] = (_Float16)(gc[j] - (float)gh[j]);
    }

    int kt = k >> 4, c = k & 15;
    _Float16* dst = Bf + (size_t)kt * 64 * 8;
    #pragma unroll 32
    for (int r = 0; r < 32; ++r) {
        int lg = r >> 3, j = r & 7;
        _Float16 v = (r < 10) ? gh[r]
                   : (r < 20) ? gl[r-10]
                   : (r < 30) ? gh[r-20]
                   : (_Float16)0.f;
        dst[((size_t)lg*16 + c)*8 + j] = v;
    }
}

// ---- single-tile A-fragment builder ----
__device__ __forceinline__ half8 gmf_build_afr1(
        const float* __restrict__ x, int pt, int lane, int N, int PTtot) {
    int lr = lane & 15;
    int lg = lane >> 4;
    int n = pt * 16 + lr;
    float x0 = 0.f, x1 = 0.f, x2 = 0.f;
    if (pt < PTtot && n < N) { x0 = x[3*n]; x1 = x[3*n+1]; x2 = x[3*n+2]; }

    float P0 = x0*x0, P1 = x1*x1, P2 = x2*x2;
    float P3 = x0*x1, P4 = x0*x2, P5 = x1*x2;

    _Float16 h0 = (_Float16)P0, h1 = (_Float16)P1, h2 = (_Float16)P2;
    _Float16 h3 = (_Float16)P3, h4 = (_Float16)P4, h5 = (_Float16)P5;
    _Float16 h6 = (_Float16)x0, h7 = (_Float16)x1, h8 = (_Float16)x2;
    _Float16 h9 = (_Float16)1.f;
    _Float16 l0 = (_Float16)(P0 - (float)h0), l1 = (_Float16)(P1 - (float)h1);
    _Float16 l2 = (_Float16)(P2 - (float)h2), l3 = (_Float16)(P3 - (float)h3);
    _Float16 l4 = (_Float16)(P4 - (float)h4), l5 = (_Float16)(P5 - (float)h5);
    _Float16 l6 = (_Float16)(x0 - (float)h6), l7 = (_Float16)(x1 - (float)h7);
    _Float16 l8 = (_Float16)(x2 - (float)h8), l9 = (_Float16)0.f;
    _Float16 z  = (_Float16)0.f;

    half8 a;
    if      (lg == 0) a = (half8){h0,h1,h2,h3,h4,h5,h6,h7};
    else if (lg == 1) a = (half8){h8,h9,h0,h1,h2,h3,h4,h5};
    else if (lg == 2) a = (half8){h6,h7,h8,h9,l0,l1,l2,l3};
    else              a = (half8){l4,l5,l6,l7,l8,l9,z,z};
    return a;
}

#define GMF_EXPACC(CC, ACC)                                                     \
    {                                                                           \
        f32x4 y = __builtin_elementwise_fma((CC), vscale, vbias);               \
        (ACC).x += __uint_as_float(cvt_u32_sat(y.x));                           \
        (ACC).y += __uint_as_float(cvt_u32_sat(y.y));                           \
        (ACC).z += __uint_as_float(cvt_u32_sat(y.z));                           \
        (ACC).w += __uint_as_float(cvt_u32_sat(y.w));                           \
    }

__device__ __forceinline__ void gmf_epilogue1(
        f32x4 a, int pt, int lane, int N, int PTtot, float* __restrict__ out) {
    int lr = lane & 15;
    int lg = lane >> 4;
    #pragma unroll
    for (int m = 1; m <= 8; m <<= 1) {   // reduce over 16 cols
        a.x += __shfl_xor(a.x, m);
        a.y += __shfl_xor(a.y, m);
        a.z += __shfl_xor(a.z, m);
        a.w += __shfl_xor(a.w, m);
    }
    if (lr == 0 && pt < PTtot) {
        int n0 = pt * 16 + lg * 4;
        if (n0     < N) out[n0]     = a.x;
        if (n0 + 1 < N) out[n0 + 1] = a.y;
        if (n0 + 2 < N) out[n0 + 2] = a.z;
        if (n0 + 3 < N) out[n0 + 3] = a.w;
    }
}

// No-split main: one wave = PT point-tiles x ALL K. One B ds_read feeds PT
// MFMAs. Double-buffered LDS staging via global_load_lds.
__global__ __launch_bounds__(256, 4) void gmf_main_ns(
        const float* __restrict__ x,
        const _Float16* __restrict__ Bfh,
        float* __restrict__ out,
        int N, int KT, int PTtot) {
    __shared__ _Float16 lbs_raw[NBUF * CHUNK * 512];   // 16 KiB

    int tid  = threadIdx.x;
    int lane = tid & 63;
    int wid  = tid >> 6;
    int pt0  = (blockIdx.x * WPB + wid) * PT;
    int pt1  = pt0 + 1;
    bool active = pt0 < PTtot;

    half8 afr0 = gmf_build_afr1(x, pt0, lane, N, PTtot);
    half8 afr1 = gmf_build_afr1(x, pt1, lane, N, PTtot);
    f32x4 acc0 = {0.f, 0.f, 0.f, 0.f};
    f32x4 acc1 = {0.f, 0.f, 0.f, 0.f};
    const f32x4 czero  = {0.f, 0.f, 0.f, 0.f};
    const f32x4 vscale = {EXP_SCALE, EXP_SCALE, EXP_SCALE, EXP_SCALE};
    const f32x4 vbias  = {EXP_BIAS,  EXP_BIAS,  EXP_BIAS,  EXP_BIAS};

    int nchunks = (KT + CHUNK - 1) / CHUNK;

#define GMF_STAGE(BUF, KBASE, NK)                                               \
    {                                                                           \
        _Pragma("unroll")                                                       \
        for (int j = 0; j < 2; ++j) {                                           \
            int tile = wid * 2 + j;                                             \
            if (tile < (NK)) {   /* wave-uniform */                             \
                const _Float16* src = Bfh + ((size_t)((KBASE) + tile)) * 512    \
                                          + lane * 8;                           \
                __builtin_amdgcn_global_load_lds(                               \
                    (const __attribute__((address_space(1))) void*)src,         \
                    (__attribute__((address_space(3))) void*)                   \
                        (lbs_raw + ((BUF) * CHUNK + tile) * 512 + lane * 8),    \
                    16, 0, 0);                                                  \
            }                                                                   \
        }                                                                       \
    }

    // Prologue: stage chunk 0 into buf 0, wait.
    {
        int nk0 = min(CHUNK, KT);
        GMF_STAGE(0, 0, nk0)
    }
    __syncthreads();   // implicit vmcnt(0) drain before s_barrier

    for (int c = 0; c < nchunks; ++c) {
        int cb = c & 1;
        int kbase = c * CHUNK;
        int nk = min(CHUNK, KT - kbase);   // uniform across block

        // Issue next chunk's loads BEFORE compute: latency hides under MFMAs.
        if (c + 1 < nchunks) {
            int nk1 = min(CHUNK, KT - (c + 1) * CHUNK);
            GMF_STAGE(cb ^ 1, (c + 1) * CHUNK, nk1)
        }

        if (active) {
            const half8* cur = (const half8*)(lbs_raw + cb * CHUNK * 512);
            if (nk == CHUNK) {
                // 2-stage rotation, full unroll (renaming removes copies).
                half8 b = cur[lane];
                f32x4 cB0 = __builtin_amdgcn_mfma_f32_16x16x32_f16(afr0, b, czero, 0, 0, 0);
                f32x4 cB1 = __builtin_amdgcn_mfma_f32_16x16x32_f16(afr1, b, czero, 0, 0, 0);
                b = cur[64 + lane];
                f32x4 cA0 = __builtin_amdgcn_mfma_f32_16x16x32_f16(afr0, b, czero, 0, 0, 0);
                f32x4 cA1 = __builtin_amdgcn_mfma_f32_16x16x32_f16(afr1, b, czero, 0, 0, 0);
                #pragma unroll
                for (int i = 2; i < CHUNK; ++i) {
                    GMF_EXPACC(cB0, acc0)
                    GMF_EXPACC(cB1, acc1)
                    cB0 = cA0; cB1 = cA1;
                    b = cur[i * 64 + lane];
                    cA0 = __builtin_amdgcn_mfma_f32_16x16x32_f16(afr0, b, czero, 0, 0, 0);
                    cA1 = __builtin_amdgcn_mfma_f32_16x16x32_f16(afr1, b, czero, 0, 0, 0);
                }
                GMF_EXPACC(cB0, acc0)
                GMF_EXPACC(cB1, acc1)
                GMF_EXPACC(cA0, acc0)
                GMF_EXPACC(cA1, acc1)
            } else {
                for (int i = 0; i < nk; ++i) {
                    half8 b = cur[i * 64 + lane];
                    f32x4 c0 = __builtin_amdgcn_mfma_f32_16x16x32_f16(afr0, b, czero, 0, 0, 0);
                    f32x4 c1 = __builtin_amdgcn_mfma_f32_16x16x32_f16(afr1, b, czero, 0, 0, 0);
                    GMF_EXPACC(c0, acc0)
                    GMF_EXPACC(c1, acc1)
                }
            }
        }

        // One barrier per chunk: drains next-chunk loads AND protects buf reuse.
        __syncthreads();
    }

    if (active) {
        gmf_epilogue1(acc0, pt0, lane, N, PTtot, out);
        gmf_epilogue1(acc1, pt1, lane, N, PTtot, out);
    }
#undef GMF_STAGE
}

extern "C" void kernel_launch(void* const* d_in, const int* in_sizes, int n_in,
                              void* d_out, int out_size, void* d_ws, size_t ws_size,
                              hipStream_t stream) {
    const float* x          = (const float*)d_in[0];
    const float* means      = (const float*)d_in[1];
    const float* log_scales = (const float*)d_in[2];
    const float* quats      = (const float*)d_in[3];
    const float* log_amps   = (const float*)d_in[4];
    float* out = (float*)d_out;

    int K = in_sizes[4];
    int N = out_size;
    int KT = (K + 15) / 16;
    int PTtot = (N + 15) / 16;

    _Float16* Bf = (_Float16*)d_ws;   // KT tiles x 1KB

    gmf_precompute<<<(KT*16 + 255) / 256, 256, 0, stream>>>(
        means, log_scales, quats, log_amps, Bf, K, KT);

    int tiles_per_block = WPB * PT;
    int blocks = (PTtot + tiles_per_block - 1) / tiles_per_block;
    gmf_main_ns<<<blocks, 256, 0, stream>>>(x, Bf, out, N, KT, PTtot);
}

// Round 20
// 36.919 us; speedup vs baseline: 2.7989x; 1.1060x over previous
//
#include <hip/hip_runtime.h>
#include <math.h>

// out[n] = sum_k exp2( t[n,k] ),  t[n,k] = sum_{j<10} P[n,j]*G[k,j]
// P = (x0^2,x1^2,x2^2, x0x1,x0x2,x1x2, x0,x1,x2, 1)
// G = h*(A00,A11,A22), 2h*(A01,A02,A12), L2E*(b0,b1,b2), h*c + log2(amp), h=-0.5*log2(e)
//
// MFMA f16 split-2 trick (one mfma_f32_16x16x32_f16 per 16x16 tile):
//   A cols [0..31] = [Phi(10) | Phi(10) | Plo(10) | 0 0]
//   B rows [0..31] = [Ghi(10) | Glo(10) | Ghi(10) | 0 0]
//
// exp2 via mean-zero Schraudolph: y = fma(t,2^23,B); v_cvt_u32_f32 saturates
// y<0 -> 0 (incl. -60000 pad gaussians); acc += bitcast<float>(u).
//
// ROUND 20 KEY CHANGE: BARRIER-FREE global-feed. The one invariant of the
// r16-r19 plateau (~39us wall vs ~10us issue) was the 16-barrier chunk
// cadence (each with full vmcnt drain, waves phase-locked). This variant:
// no-split + PT=2 + each wave streams all KT B-tiles from L2 with a 4-deep
// register prefetch. No LDS, no __syncthreads after afr build. L2 traffic
// 512MB ~ 15us aggregate, overlapped with ~10us VALU.

typedef _Float16 half8 __attribute__((ext_vector_type(8)));
typedef float    f32x4 __attribute__((ext_vector_type(4)));

#define WPB     4    // waves per block
#define PT      2    // point-tiles per wave

#define EXP_SCALE 8388608.0f        // 2^23
#define EXP_BIAS  1064880938.0f     // (127 - 0.0563) * 2^23, mean-zero bias

__device__ __forceinline__ unsigned cvt_u32_sat(float y) {
    unsigned u;
    asm("v_cvt_u32_f32 %0, %1" : "=v"(u) : "v"(y));   // saturates: y<0 -> 0
    return u;
}

__global__ __launch_bounds__(256) void gmf_precompute(
        const float* __restrict__ means,
        const float* __restrict__ log_scales,
        const float* __restrict__ quats,
        const float* __restrict__ log_amps,
        _Float16* __restrict__ Bf, int K, int KT) {
    int k = blockIdx.x * blockDim.x + threadIdx.x;
    if (k >= KT * 16) return;

    float gc[10];
    if (k < K) {
        float qw = quats[4*k+0], qx = quats[4*k+1], qy = quats[4*k+2], qz = quats[4*k+3];
        float qn = rsqrtf(qw*qw + qx*qx + qy*qy + qz*qz);
        qw *= qn; qx *= qn; qy *= qn; qz *= qn;

        float r00 = 1.f - 2.f*(qy*qy + qz*qz);
        float r01 = 2.f*(qx*qy - qw*qz);
        float r02 = 2.f*(qx*qz + qw*qy);
        float r10 = 2.f*(qx*qy + qw*qz);
        float r11 = 1.f - 2.f*(qx*qx + qz*qz);
        float r12 = 2.f*(qy*qz - qw*qx);
        float r20 = 2.f*(qx*qz - qw*qy);
        float r21 = 2.f*(qy*qz + qw*qx);
        float r22 = 1.f - 2.f*(qx*qx + qy*qy);

        float s0 = fminf(fmaxf(expf(log_scales[3*k+0]), 1e-5f), 100.f);
        float s1 = fminf(fmaxf(expf(log_scales[3*k+1]), 1e-5f), 100.f);
        float s2 = fminf(fmaxf(expf(log_scales[3*k+2]), 1e-5f), 100.f);
        float v0 = s0*s0, v1 = s1*s1, v2 = s2*s2;

        float S00 = r00*r00*v0 + r01*r01*v1 + r02*r02*v2 + 1e-5f;
        float S11 = r10*r10*v0 + r11*r11*v1 + r12*r12*v2 + 1e-5f;
        float S22 = r20*r20*v0 + r21*r21*v1 + r22*r22*v2 + 1e-5f;
        float S01 = r00*r10*v0 + r01*r11*v1 + r02*r12*v2;
        float S02 = r00*r20*v0 + r01*r21*v1 + r02*r22*v2;
        float S12 = r10*r20*v0 + r11*r21*v1 + r12*r22*v2;

        float c00 = S11*S22 - S12*S12;
        float c01 = S02*S12 - S01*S22;
        float c02 = S01*S12 - S02*S11;
        float det = S00*c00 + S01*c01 + S02*c02;
        float id  = 1.f/det;
        float A00 = c00*id, A01 = c01*id, A02 = c02*id;
        float A11 = (S00*S22 - S02*S02)*id;
        float A12 = (S01*S02 - S00*S12)*id;
        float A22 = (S00*S11 - S01*S01)*id;

        float m0 = means[3*k+0], m1 = means[3*k+1], m2 = means[3*k+2];
        float b0 = A00*m0 + A01*m1 + A02*m2;
        float b1 = A01*m0 + A11*m1 + A12*m2;
        float b2 = A02*m0 + A12*m1 + A22*m2;
        float cc = b0*m0 + b1*m1 + b2*m2;

        float la = fminf(fmaxf(log_amps[k], -10.f), 6.f);
        const float L2E = 1.4426950408889634f;
        const float h = -0.5f * L2E;

        gc[0] = h*A00; gc[1] = h*A11; gc[2] = h*A22;
        gc[3] = 2.f*h*A01; gc[4] = 2.f*h*A02; gc[5] = 2.f*h*A12;
        gc[6] = L2E*b0; gc[7] = L2E*b1; gc[8] = L2E*b2;
        gc[9] = h*cc + L2E*la;
    } else {
        #pragma unroll
        for (int j = 0; j < 10; ++j) gc[j] = 0.f;
        gc[9] = -60000.f;   // pad gaussian -> saturates to 0 in fast exp2
    }

    _Float16 gh[10], gl[10];
    #pragma unroll
    for (int j = 0; j < 10; ++j) {
        gh[j] = (_Float16)gc[j];
        gl[j] = (_Float16)(gc[j] - (float)gh[j]);
    }

    int kt = k >> 4, c = k & 15;
    _Float16* dst = Bf + (size_t)kt * 64 * 8;
    #pragma unroll 32
    for (int r = 0; r < 32; ++r) {
        int lg = r >> 3, j = r & 7;
        _Float16 v = (r < 10) ? gh[r]
                   : (r < 20) ? gl[r-10]
                   : (r < 30) ? gh[r-20]
                   : (_Float16)0.f;
        dst[((size_t)lg*16 + c)*8 + j] = v;
    }
}

// ---- single-tile A-fragment builder ----
__device__ __forceinline__ half8 gmf_build_afr1(
        const float* __restrict__ x, int pt, int lane, int N, int PTtot) {
    int lr = lane & 15;
    int lg = lane >> 4;
    int n = pt * 16 + lr;
    float x0 = 0.f, x1 = 0.f, x2 = 0.f;
    if (pt < PTtot && n < N) { x0 = x[3*n]; x1 = x[3*n+1]; x2 = x[3*n+2]; }

    float P0 = x0*x0, P1 = x1*x1, P2 = x2*x2;
    float P3 = x0*x1, P4 = x0*x2, P5 = x1*x2;

    _Float16 h0 = (_Float16)P0, h1 = (_Float16)P1, h2 = (_Float16)P2;
    _Float16 h3 = (_Float16)P3, h4 = (_Float16)P4, h5 = (_Float16)P5;
    _Float16 h6 = (_Float16)x0, h7 = (_Float16)x1, h8 = (_Float16)x2;
    _Float16 h9 = (_Float16)1.f;
    _Float16 l0 = (_Float16)(P0 - (float)h0), l1 = (_Float16)(P1 - (float)h1);
    _Float16 l2 = (_Float16)(P2 - (float)h2), l3 = (_Float16)(P3 - (float)h3);
    _Float16 l4 = (_Float16)(P4 - (float)h4), l5 = (_Float16)(P5 - (float)h5);
    _Float16 l6 = (_Float16)(x0 - (float)h6), l7 = (_Float16)(x1 - (float)h7);
    _Float16 l8 = (_Float16)(x2 - (float)h8), l9 = (_Float16)0.f;
    _Float16 z  = (_Float16)0.f;

    half8 a;
    if      (lg == 0) a = (half8){h0,h1,h2,h3,h4,h5,h6,h7};
    else if (lg == 1) a = (half8){h8,h9,h0,h1,h2,h3,h4,h5};
    else if (lg == 2) a = (half8){h6,h7,h8,h9,l0,l1,l2,l3};
    else              a = (half8){l4,l5,l6,l7,l8,l9,z,z};
    return a;
}

#define GMF_EXPACC(CC, ACC)                                                     \
    {                                                                           \
        f32x4 y = __builtin_elementwise_fma((CC), vscale, vbias);               \
        (ACC).x += __uint_as_float(cvt_u32_sat(y.x));                           \
        (ACC).y += __uint_as_float(cvt_u32_sat(y.y));                           \
        (ACC).z += __uint_as_float(cvt_u32_sat(y.z));                           \
        (ACC).w += __uint_as_float(cvt_u32_sat(y.w));                           \
    }

__device__ __forceinline__ void gmf_epilogue1(
        f32x4 a, int pt, int lane, int N, int PTtot, float* __restrict__ out) {
    int lr = lane & 15;
    int lg = lane >> 4;
    #pragma unroll
    for (int m = 1; m <= 8; m <<= 1) {   // reduce over 16 cols
        a.x += __shfl_xor(a.x, m);
        a.y += __shfl_xor(a.y, m);
        a.z += __shfl_xor(a.z, m);
        a.w += __shfl_xor(a.w, m);
    }
    if (lr == 0 && pt < PTtot) {
        int n0 = pt * 16 + lg * 4;
        if (n0     < N) out[n0]     = a.x;
        if (n0 + 1 < N) out[n0 + 1] = a.y;
        if (n0 + 2 < N) out[n0 + 2] = a.z;
        if (n0 + 3 < N) out[n0 + 3] = a.w;
    }
}

#define GMF_MF2(C0, C1, BB)                                                     \
    C0 = __builtin_amdgcn_mfma_f32_16x16x32_f16(afr0, (BB), czero, 0, 0, 0);    \
    C1 = __builtin_amdgcn_mfma_f32_16x16x32_f16(afr1, (BB), czero, 0, 0, 0);

// Barrier-free global-feed main: one wave = PT point-tiles x ALL K.
// 4-deep register B prefetch from L2; zero LDS, zero barriers.
__global__ __launch_bounds__(256, 4) void gmf_main_gf(
        const float* __restrict__ x,
        const half8* __restrict__ Bf,   // padded +4 tiles
        float* __restrict__ out,
        int N, int KT, int PTtot) {
    int tid  = threadIdx.x;
    int lane = tid & 63;
    int wid  = tid >> 6;
    int pt0  = (blockIdx.x * WPB + wid) * PT;
    int pt1  = pt0 + 1;
    if (pt0 >= PTtot) return;

    half8 afr0 = gmf_build_afr1(x, pt0, lane, N, PTtot);
    half8 afr1 = gmf_build_afr1(x, pt1, lane, N, PTtot);
    f32x4 acc0 = {0.f, 0.f, 0.f, 0.f};
    f32x4 acc1 = {0.f, 0.f, 0.f, 0.f};
    const f32x4 czero  = {0.f, 0.f, 0.f, 0.f};
    const f32x4 vscale = {EXP_SCALE, EXP_SCALE, EXP_SCALE, EXP_SCALE};
    const f32x4 vbias  = {EXP_BIAS,  EXP_BIAS,  EXP_BIAS,  EXP_BIAS};

    const half8* bp = Bf + lane;

    // 4-deep prologue (Bf padded +4 tiles: all prefetch indices in-bounds).
    half8 b0 = bp[0 * 64];
    half8 b1 = bp[1 * 64];
    half8 b2 = bp[2 * 64];
    half8 b3 = bp[3 * 64];

    f32x4 c0, c1, d0, d1;
    int kt = 0;
    for (; kt + 3 < KT; kt += 4) {
        // Prefetch next quad early (values unused past KT; in-bounds via pad).
        half8 n0 = bp[(size_t)(kt + 4) * 64];
        half8 n1 = bp[(size_t)(kt + 5) * 64];
        half8 n2 = bp[(size_t)(kt + 6) * 64];
        half8 n3 = bp[(size_t)(kt + 7) * 64];

        GMF_MF2(c0, c1, b0)
        GMF_MF2(d0, d1, b1)
        GMF_EXPACC(c0, acc0) GMF_EXPACC(c1, acc1)
        GMF_MF2(c0, c1, b2)
        GMF_EXPACC(d0, acc0) GMF_EXPACC(d1, acc1)
        GMF_MF2(d0, d1, b3)
        GMF_EXPACC(c0, acc0) GMF_EXPACC(c1, acc1)
        GMF_EXPACC(d0, acc0) GMF_EXPACC(d1, acc1)

        b0 = n0; b1 = n1; b2 = n2; b3 = n3;
    }
    // Tail (KT % 4 tiles already resident in b0..b2).
    int rem = KT - kt;
    if (rem > 0) {
        GMF_MF2(c0, c1, b0)
        GMF_EXPACC(c0, acc0) GMF_EXPACC(c1, acc1)
    }
    if (rem > 1) {
        GMF_MF2(c0, c1, b1)
        GMF_EXPACC(c0, acc0) GMF_EXPACC(c1, acc1)
    }
    if (rem > 2) {
        GMF_MF2(c0, c1, b2)
        GMF_EXPACC(c0, acc0) GMF_EXPACC(c1, acc1)
    }

    gmf_epilogue1(acc0, pt0, lane, N, PTtot, out);
    gmf_epilogue1(acc1, pt1, lane, N, PTtot, out);
}

extern "C" void kernel_launch(void* const* d_in, const int* in_sizes, int n_in,
                              void* d_out, int out_size, void* d_ws, size_t ws_size,
                              hipStream_t stream) {
    const float* x          = (const float*)d_in[0];
    const float* means      = (const float*)d_in[1];
    const float* log_scales = (const float*)d_in[2];
    const float* quats      = (const float*)d_in[3];
    const float* log_amps   = (const float*)d_in[4];
    float* out = (float*)d_out;

    int K = in_sizes[4];
    int N = out_size;
    int KT = (K + 15) / 16;
    int PTtot = (N + 15) / 16;

    _Float16* Bf = (_Float16*)d_ws;   // (KT+4) tiles x 1KB; last 4 = pad

    gmf_precompute<<<(KT*16 + 255) / 256, 256, 0, stream>>>(
        means, log_scales, quats, log_amps, Bf, K, KT);

    int tiles_per_block = WPB * PT;
    int blocks = (PTtot + tiles_per_block - 1) / tiles_per_block;
    gmf_main_gf<<<blocks, 256, 0, stream>>>(x, (const half8*)Bf, out, N, KT, PTtot);
}